// Round 6
// baseline (297.249 us; speedup 1.0000x reference)
//
#include <hip/hip_runtime.h>

// DfOpCoefLoop: deep-filtering over first 96 freq bins, 5-tap complex FIR in
// time (lookahead 2), alpha-blended with dry spec; remaining bins copied.
//
// spec  : (B=32, 1, T=1000, F=481, 2) f32   = 123.1 MB   (row = 962 f32 = 3848 B)
// coefs : (B=32, T=1000, ORDER=5, DF=96, 2) = 122.9 MB   (row = 960 f32)
// alpha : (B=32, T=1000, 1) f32
// out   : same shape as spec                = 123.1 MB
//
// R4: 32000 one-row blocks, f2    -> 77 us (3.1 TB/s HBM, latency-structure-bound)
// R5: + f4 coefs/tail             -> 81 us (no help; MLP per wave still ~1)
// R6: ~3200 long-lived specialized blocks, grid-chunked, unrolled -> target 62-70 us.

typedef float f2 __attribute__((ext_vector_type(2)));
typedef float f4 __attribute__((ext_vector_type(4)));

#define ORDER 5
#define TPAD  2          // ORDER - LOOKAHEAD - 1
#define NDF   96
#define NF    481
#define TT    1000
#define BB    32
#define NROWS (BB * TT)  // 32000
#define ROWF  (NF * 2)   // 962 floats per spec/out row
#define CROWF (ORDER * NDF * 2)  // 960 floats per coef row

// ---- copy section: tail bins [96,481) of every row = 385 f2 units/row ----
#define TAILF2   385
#define COPY_U   (NROWS * TAILF2)   // 12,320,000 f2 units
#define CPB      6400               // f2 units per copy block (25 iters x 256)
#define NCOPY    (COPY_U / CPB)     // 1925 blocks (exact)

// ---- DF section: 25 contiguous rows per block, 5 rows x 48 bin-pairs/iter ----
#define RPB      25
#define NDFB     (NROWS / RPB)      // 1280 blocks

__global__ __launch_bounds__(256) void df_kernel(
    const float* __restrict__ spec,
    const float* __restrict__ coefs,
    const float* __restrict__ alpha,
    float* __restrict__ out)
{
    const int tid = threadIdx.x;

    if (blockIdx.x < NCOPY) {
        // ================= tail copy: pure streaming =================
        const unsigned base = (unsigned)blockIdx.x * CPB + tid;
#pragma unroll 5
        for (int it = 0; it < CPB / 256; ++it) {
            const unsigned u   = base + it * 256;      // < 12,320,000 (exact fit)
            const unsigned row = u / TAILF2;           // magic-mul div
            const unsigned k   = u - row * TAILF2;
            const float* sp = spec + (size_t)row * ROWF + 192 + 2 * k;
            float*       op = out  + (size_t)row * ROWF + 192 + 2 * k;
            const f2 v = __builtin_nontemporal_load((const f2*)sp);
            __builtin_nontemporal_store(v, (f2*)op);
        }
    } else {
        // ================= DF section =================
        const int db   = blockIdx.x - NCOPY;       // 0..1279
        const int lane = tid % 48;                 // bin-pair (2*lane, 2*lane+1)
        const int ro   = tid / 48;                 // row offset 0..4 (5 -> idle)
        if (ro < 5) {
            const int r0 = db * RPB;               // block owns rows [r0, r0+25)
#pragma unroll
            for (int it = 0; it < RPB / 5; ++it) {
                const int row = r0 + it * 5 + ro;
                const int t   = row % TT;
                const float* __restrict__ srow = spec  + (size_t)row * ROWF;
                const float* __restrict__ crow = coefs + (size_t)row * CROWF;
                float*       __restrict__ orow = out   + (size_t)row * ROWF;

                const float a   = alpha[row];
                const float oma = 1.0f - a;

                float re0 = 0.f, im0 = 0.f, re1 = 0.f, im1 = 0.f;
                f2 s0 = {0.f, 0.f}, s1 = {0.f, 0.f};
#pragma unroll
                for (int i = 0; i < ORDER; ++i) {
                    const int ts = t + i - TPAD;   // zero-pad outside [0,T)
                    if (ts >= 0 && ts < TT) {
                        const float* w = spec + (size_t)(row + i - TPAD) * ROWF + 4 * lane;
                        const f2 w0 = *(const f2*)(w);      // always 8B-aligned
                        const f2 w1 = *(const f2*)(w + 2);
                        const f4 c  = __builtin_nontemporal_load(
                            (const f4*)(crow + i * (NDF * 2) + 4 * lane));
                        re0 += w0.x * c.x - w0.y * c.y;
                        im0 += w0.y * c.x + w0.x * c.y;
                        re1 += w1.x * c.z - w1.y * c.w;
                        im1 += w1.y * c.z + w1.x * c.w;
                        if (i == TPAD) { s0 = w0; s1 = w1; }  // center tap (always valid)
                    }
                }
                f2 o0, o1;
                o0.x = re0 * a + s0.x * oma;  o0.y = im0 * a + s0.y * oma;
                o1.x = re1 * a + s1.x * oma;  o1.y = im1 * a + s1.y * oma;
                __builtin_nontemporal_store(o0, (f2*)(orow + 4 * lane));
                __builtin_nontemporal_store(o1, (f2*)(orow + 4 * lane + 2));
            }
        }
    }
}

extern "C" void kernel_launch(void* const* d_in, const int* in_sizes, int n_in,
                              void* d_out, int out_size, void* d_ws, size_t ws_size,
                              hipStream_t stream) {
    const float* spec  = (const float*)d_in[0];
    const float* coefs = (const float*)d_in[1];
    const float* alpha = (const float*)d_in[2];
    float* out = (float*)d_out;

    dim3 grid(NCOPY + NDFB);   // 1925 copy blocks + 1280 DF blocks
    dim3 block(256);
    df_kernel<<<grid, block, 0, stream>>>(spec, coefs, alpha, out);
}